// Round 1
// baseline (509.863 us; speedup 1.0000x reference)
//
#include <hip/hip_runtime.h>
#include <math.h>

// ws layout (uint32 words):
//   [0 .. 2^20)            hist20
//   [2^20 .. 2^20+4096)    hist12
//   [.. +1024)             csum (chunk sums of hist20)
//   [.. +8)                ctrl: [0]=b12 (uint, 0xFFFFFFFF = none)
//                                [1]=kprime
//                                [2]=thr_bits (float threshold as bits)
#define HIST20_WORDS (1u << 20)
#define HIST12_OFF   (HIST20_WORDS)
#define CSUM_OFF     (HIST20_WORDS + 4096u)
#define CTRL_OFF     (CSUM_OFF + 1024u)
#define WS_WORDS     (CTRL_OFF + 8u)

// --- softplus implementations -------------------------------------------
// Reference (jax.nn.softplus = jnp.logaddexp(x,0)) computes, all in f32:
//   m = max(x,0); e = exp_f32(-|x|); l = log1p_f32(e); result = m + l
// "exact": each f32 step produced by double-precision evaluation then
// rounded to f32 (correctly-rounded f32 steps, mimicking the composition).
__device__ __forceinline__ float softplus_exact(float x) {
    float ax = fabsf(x);
    float e = (float)exp(-(double)ax);       // correctly-rounded f32 exp
    float l = (float)log1p((double)e);       // correctly-rounded f32 log1p
    return fmaxf(x, 0.0f) + l;
}

// fast approximate version (~2-3 ulp); used only away from the threshold
__device__ __forceinline__ float softplus_cheap(float x) {
    float ax = fabsf(x);
    float e = __expf(-ax);
    float l = log1pf(e);
    return fmaxf(x, 0.0f) + l;
}

// --- K1: 12-bit (top bits) histogram of exact unknown-loss bits ----------
__global__ __launch_bounds__(256) void k1_hist12(
    const float* __restrict__ lg, const float* __restrict__ tg,
    unsigned* __restrict__ ws, long long n) {
    __shared__ unsigned sh[4096];
    for (int i = threadIdx.x; i < 4096; i += 256) sh[i] = 0;
    __syncthreads();

    long long n4 = n >> 2;
    long long tid = (long long)blockIdx.x * 256 + threadIdx.x;
    long long stride = (long long)gridDim.x * 256;
    const float4* lg4 = (const float4*)lg;
    const float4* tg4 = (const float4*)tg;

    for (long long i = tid; i < n4; i += stride) {
        float4 x4 = lg4[i];
        float4 t4 = tg4[i];
        float xs[4] = {x4.x, x4.y, x4.z, x4.w};
        float ts[4] = {t4.x, t4.y, t4.z, t4.w};
#pragma unroll
        for (int c = 0; c < 4; ++c) {
            if (isnan(ts[c])) {
                float sp = softplus_exact(xs[c]);
                unsigned b = __float_as_uint(sp);
                if (b != 0u && b != 0x80000000u)   // count_nonzero semantics
                    atomicAdd(&sh[b >> 20], 1u);
            }
        }
    }
    if (tid == 0) {  // scalar tail (none for N=2^25, kept for generality)
        for (long long i = (n4 << 2); i < n; ++i) {
            if (isnan(tg[i])) {
                float sp = softplus_exact(lg[i]);
                unsigned b = __float_as_uint(sp);
                if (b != 0u && b != 0x80000000u) atomicAdd(&sh[b >> 20], 1u);
            }
        }
    }
    __syncthreads();
    unsigned* hist12 = ws + HIST12_OFF;
    for (int i = threadIdx.x; i < 4096; i += 256)
        if (sh[i]) atomicAdd(&hist12[i], sh[i]);   // only ~100 bins nonzero
}

// --- K2: select 12-bit bin containing the k-th largest -------------------
__global__ __launch_bounds__(256) void k2_sel12(
    unsigned* __restrict__ ws, const int* __restrict__ epoch_ptr) {
    const unsigned* hist12 = ws + HIST12_OFF;
    unsigned* ctrl = ws + CTRL_OFF;
    __shared__ unsigned long long chunk[256];
    int t = threadIdx.x;
    unsigned long long s = 0;
    for (int j = 0; j < 16; ++j) s += hist12[t * 16 + j];
    chunk[t] = s;
    __syncthreads();
    if (t == 0) {
        unsigned long long tot = 0;
        for (int c = 0; c < 256; ++c) tot += chunk[c];
        // mimic: percent = min(epoch*0.1, 1.0) in f32;
        //        k = round(float(n) * percent) -> int32; k = max(k, 1)
        int epoch = epoch_ptr[0];
        float percent = fminf((float)epoch * 0.1f, 1.0f);
        float nf = (float)tot;              // astype(float32), RN
        float kr = rintf(nf * percent);     // jnp.round = half-to-even
        long long k = (long long)kr;        // astype(int32) truncation
        if (k < 1) k = 1;

        long long cum = 0;
        int b = -1;
        long long kprime = 0;
        for (int c = 255; c >= 0; --c) {
            if (cum + (long long)chunk[c] >= k) {
                long long cc = cum;
                for (int j = 15; j >= 0; --j) {
                    unsigned v = hist12[c * 16 + j];
                    if (cc + (long long)v >= k) {
                        b = c * 16 + j;
                        kprime = k - cc;
                        break;
                    }
                    cc += v;
                }
                break;
            }
            cum += chunk[c];
        }
        ctrl[0] = (unsigned)b;              // 0xFFFFFFFF if no positives
        ctrl[1] = (unsigned)kprime;
        if (b < 0) ctrl[2] = 0u;            // threshold = 0.0f
    }
}

// --- K3: 20-bit (low bits) histogram within the selected bin -------------
__global__ __launch_bounds__(256) void k3_hist20(
    const float* __restrict__ lg, const float* __restrict__ tg,
    unsigned* __restrict__ ws, long long n) {
    const unsigned* ctrl = ws + CTRL_OFF;
    int b12 = (int)ctrl[0];
    if (b12 < 0) return;
    unsigned lo = (unsigned)b12 << 20;
    unsigned hi = lo + (1u << 20);          // b12 < 4095 for real data
    float flo = __uint_as_float(lo);
    float fhi = (b12 >= 4095) ? __builtin_inff() : __uint_as_float(hi);
    // cheap-filter window (cheap softplus is within ~4e-7 rel of exact)
    float wlo = flo - (fabsf(flo) * 1e-4f + 1e-6f);
    float whi = (b12 >= 4095) ? __builtin_inff()
                              : fhi + (fabsf(fhi) * 1e-4f + 1e-6f);

    long long n4 = n >> 2;
    long long tid = (long long)blockIdx.x * 256 + threadIdx.x;
    long long stride = (long long)gridDim.x * 256;
    const float4* lg4 = (const float4*)lg;
    const float4* tg4 = (const float4*)tg;

    for (long long i = tid; i < n4; i += stride) {
        float4 x4 = lg4[i];
        float4 t4 = tg4[i];
        float xs[4] = {x4.x, x4.y, x4.z, x4.w};
        float ts[4] = {t4.x, t4.y, t4.z, t4.w};
#pragma unroll
        for (int c = 0; c < 4; ++c) {
            if (isnan(ts[c])) {
                float spc = softplus_cheap(xs[c]);
                if (spc >= wlo && spc <= whi) {
                    float sp = softplus_exact(xs[c]);
                    unsigned b = __float_as_uint(sp);
                    if (b >= lo && b < hi && b != 0u && b != 0x80000000u)
                        atomicAdd(&ws[b - lo], 1u);
                }
            }
        }
    }
    if (tid == 0) {
        for (long long i = (n4 << 2); i < n; ++i) {
            if (isnan(tg[i])) {
                float sp = softplus_exact(lg[i]);
                unsigned b = __float_as_uint(sp);
                if (b >= lo && b < hi && b != 0u && b != 0x80000000u)
                    atomicAdd(&ws[b - lo], 1u);
            }
        }
    }
}

// --- K4a: chunk sums of hist20 (1024 chunks x 1024 bins) -----------------
__global__ __launch_bounds__(256) void k4a_csum(unsigned* __restrict__ ws) {
    __shared__ unsigned red[256];
    int b = blockIdx.x;
    const unsigned* base = ws + (size_t)b * 1024;
    unsigned s = 0;
    for (int j = threadIdx.x; j < 1024; j += 256) s += base[j];
    red[threadIdx.x] = s;
    __syncthreads();
    for (int off = 128; off > 0; off >>= 1) {
        if (threadIdx.x < off) red[threadIdx.x] += red[threadIdx.x + off];
        __syncthreads();
    }
    if (threadIdx.x == 0) ws[CSUM_OFF + b] = red[0];
}

// --- K4b: exact threshold bits from hist20 -------------------------------
__global__ __launch_bounds__(1024) void k4b_sel20(unsigned* __restrict__ ws) {
    unsigned* ctrl = ws + CTRL_OFF;
    __shared__ unsigned long long csum[1024];
    __shared__ unsigned bins[1024];
    __shared__ int selc;
    __shared__ long long rem;
    int t = threadIdx.x;
    int b12 = (int)ctrl[0];
    if (b12 < 0) {
        if (t == 0) ctrl[2] = 0u;
        return;
    }
    csum[t] = ws[CSUM_OFF + t];
    __syncthreads();
    if (t == 0) {
        long long k = (long long)ctrl[1];
        long long cum = 0;
        selc = -1;
        for (int c = 1023; c >= 0; --c) {
            if (cum + (long long)csum[c] >= k) {
                selc = c;
                rem = k - cum;
                break;
            }
            cum += csum[c];
        }
    }
    __syncthreads();
    int c = selc;
    if (c < 0) {             // should not happen (K1/K3 use same exact fn)
        if (t == 0) ctrl[2] = 0u;
        return;
    }
    bins[t] = ws[(size_t)c * 1024 + t];
    __syncthreads();
    if (t == 0) {
        long long r = rem;
        long long cum = 0;
        int bsel = 0;
        for (int j = 1023; j >= 0; --j) {
            if (cum + (long long)bins[j] >= r) {
                bsel = j;
                break;
            }
            cum += bins[j];
        }
        ctrl[2] = ((unsigned)b12 << 20) | (unsigned)(c * 1024 + bsel);
    }
}

// --- K5: final output pass ----------------------------------------------
__global__ __launch_bounds__(256) void k5_final(
    const float* __restrict__ lg, const float* __restrict__ tg,
    float* __restrict__ out, const unsigned* __restrict__ ws, long long n) {
    const unsigned* ctrl = ws + CTRL_OFF;
    float thr = __uint_as_float(ctrl[2]);
    float band = fabsf(thr) * 1e-4f + 1e-6f;  // exact-recheck band

    long long n4 = n >> 2;
    long long tid = (long long)blockIdx.x * 256 + threadIdx.x;
    long long stride = (long long)gridDim.x * 256;
    const float4* lg4 = (const float4*)lg;
    const float4* tg4 = (const float4*)tg;
    float4* out4 = (float4*)out;

    for (long long i = tid; i < n4; i += stride) {
        float4 x4 = lg4[i];
        float4 t4 = tg4[i];
        float xs[4] = {x4.x, x4.y, x4.z, x4.w};
        float ts[4] = {t4.x, t4.y, t4.z, t4.w};
        float os[4];
#pragma unroll
        for (int c = 0; c < 4; ++c) {
            float x = xs[c], t = ts[c];
            bool unk = isnan(t);
            float spc = softplus_cheap(x);
            if (unk) {
                float loss = (fabsf(spc - thr) <= band) ? softplus_exact(x)
                                                        : spc;
                os[c] = (loss > thr) ? 0.0f : loss;   // losses * {0,1}
            } else {
                os[c] = spc - x * t;                  // lambda == 1
            }
        }
        float4 o = {os[0], os[1], os[2], os[3]};
        out4[i] = o;
    }
    if (tid == 0) {
        for (long long i = (n4 << 2); i < n; ++i) {
            float x = lg[i], t = tg[i];
            bool unk = isnan(t);
            if (unk) {
                float loss = softplus_exact(x);
                out[i] = (loss > thr) ? 0.0f : loss;
            } else {
                out[i] = softplus_exact(x) - x * t;
            }
        }
    }
}

extern "C" void kernel_launch(void* const* d_in, const int* in_sizes, int n_in,
                              void* d_out, int out_size, void* d_ws, size_t ws_size,
                              hipStream_t stream) {
    const float* lg = (const float*)d_in[0];
    const float* tg = (const float*)d_in[1];
    const int* epoch = (const int*)d_in[2];
    float* out = (float*)d_out;
    unsigned* ws = (unsigned*)d_ws;
    long long n = (long long)in_sizes[0];

    // zero hist12 + hist20 + csum + ctrl every call (graph-capture safe)
    hipMemsetAsync(d_ws, 0, (size_t)WS_WORDS * 4, stream);

    const int blocks = 2048, threads = 256;
    k1_hist12<<<blocks, threads, 0, stream>>>(lg, tg, ws, n);
    k2_sel12<<<1, 256, 0, stream>>>(ws, epoch);
    k3_hist20<<<blocks, threads, 0, stream>>>(lg, tg, ws, n);
    k4a_csum<<<1024, 256, 0, stream>>>(ws);
    k4b_sel20<<<1, 1024, 0, stream>>>(ws);
    k5_final<<<blocks, threads, 0, stream>>>(lg, tg, out, ws, n);
}